// Round 4
// baseline (124.298 us; speedup 1.0000x reference)
//
#include <hip/hip_runtime.h>

#define BLOCK 256

// ---------------------------------------------------------------------------
// Kernel 1: per-face precompute + counter zeroing.
//   cent[f] = centroid (xyz)
//   g0[f] = (gv.xyz, cv)  with  gv = A*e0 - B*e1,  cv = B*w1e1 - A*w1e0
//   g1[f] = (gw.xyz, cw)  with  gw = C*e1 - B*e0,  cw = B*w1e0 - C*w1e1
// so that for a sample point s:  v = dot(s,gv)+cv,  w = dot(s,gw)+cw,
// u = 1-v-w   (A=d11/denom, B=d01/denom, C=d00/denom).
// ---------------------------------------------------------------------------
__global__ void face_pre_kernel(const float* __restrict__ verts,
                                const int* __restrict__ faces,
                                int F,
                                float4* __restrict__ cent,
                                float4* __restrict__ g0,
                                float4* __restrict__ g1,
                                int* __restrict__ done1,   // 32 counters, stride 32 ints
                                int* __restrict__ done2) {
    if (blockIdx.x == 0) {
        if (threadIdx.x < 32) done1[threadIdx.x * 32] = 0;
        if (threadIdx.x == 32) done2[0] = 0;
    }
    int f = blockIdx.x * blockDim.x + threadIdx.x;
    if (f >= F) return;
    int i0 = faces[3 * f + 0];
    int i1 = faces[3 * f + 1];
    int i2 = faces[3 * f + 2];
    float ax = verts[3 * i0 + 0], ay = verts[3 * i0 + 1], az = verts[3 * i0 + 2];
    float bx = verts[3 * i1 + 0], by = verts[3 * i1 + 1], bz = verts[3 * i1 + 2];
    float cx = verts[3 * i2 + 0], cy = verts[3 * i2 + 1], cz = verts[3 * i2 + 2];

    float e0x = bx - ax, e0y = by - ay, e0z = bz - az;
    float e1x = cx - ax, e1y = cy - ay, e1z = cz - az;

    float d00 = e0x * e0x + e0y * e0y + e0z * e0z;
    float d01 = e0x * e1x + e0y * e1y + e0z * e1z;
    float d11 = e1x * e1x + e1y * e1y + e1z * e1z;
    float inv = 1.0f / (d00 * d11 - d01 * d01);
    float A = d11 * inv, B = d01 * inv, C = d00 * inv;

    float w1e0 = ax * e0x + ay * e0y + az * e0z;
    float w1e1 = ax * e1x + ay * e1y + az * e1z;

    const float third = 1.0f / 3.0f;
    cent[f] = make_float4((ax + bx + cx) * third,
                          (ay + by + cy) * third,
                          (az + bz + cz) * third, 0.0f);
    g0[f] = make_float4(A * e0x - B * e1x, A * e0y - B * e1y, A * e0z - B * e1z,
                        B * w1e1 - A * w1e0);
    g1[f] = make_float4(C * e1x - B * e0x, C * e1y - B * e0y, C * e1z - B * e0z,
                        B * w1e0 - C * w1e1);
}

__device__ __forceinline__ float sgpr_broadcast(float v) {
    union { float f; int i; } u;
    u.f = v;
    u.i = __builtin_amdgcn_readfirstlane(u.i);
    return u.f;
}

// ---------------------------------------------------------------------------
// Kernel 2: pair kernel + fused final reduction (last-block-done).
// One block per i. Prologue: compute i's 10 sample points + centroid into
// SGPRs. j-loop: 3 float4 loads + dist test + 10 branchless sample tests.
// Epilogue: block count -> partial[i] (release store); two-level done
// counters; last block reduces all partials -> out[0].
// ---------------------------------------------------------------------------
template <int SS>
__global__ void __launch_bounds__(BLOCK)
pair_kernel(const float4* __restrict__ cent,
            const float4* __restrict__ g0,
            const float4* __restrict__ g1,
            const float* __restrict__ verts,
            const int* __restrict__ faces,
            const float* __restrict__ alpha,
            const float* __restrict__ beta,
            const float* __restrict__ face_probs,
            int F,
            float* __restrict__ partial,
            int* __restrict__ done1,
            int* __restrict__ done2,
            float* __restrict__ out) {
    const int i = blockIdx.x;
    const int tid = threadIdx.x;

    // ---- uniform prologue: i's vertices, centroid, SS sample points ----
    int i0 = faces[3 * i + 0];
    int i1 = faces[3 * i + 1];
    int i2 = faces[3 * i + 2];
    float ax = verts[3 * i0 + 0], ay = verts[3 * i0 + 1], az = verts[3 * i0 + 2];
    float bx = verts[3 * i1 + 0], by = verts[3 * i1 + 1], bz = verts[3 * i1 + 2];
    float cx = verts[3 * i2 + 0], cy = verts[3 * i2 + 1], cz = verts[3 * i2 + 2];

    const float third = 1.0f / 3.0f;
    float cix = sgpr_broadcast((ax + bx + cx) * third);
    float ciy = sgpr_broadcast((ay + by + cy) * third);
    float ciz = sgpr_broadcast((az + bz + cz) * third);

    float sx[SS], sy[SS], sz[SS];
#pragma unroll
    for (int s = 0; s < SS; ++s) {
        float al = alpha[i * SS + s];
        float be = beta[i * SS + s];
        float ga = 1.0f - al - be;
        sx[s] = sgpr_broadcast(al * ax + be * bx + ga * cx);
        sy[s] = sgpr_broadcast(al * ay + be * by + ga * cy);
        sz[s] = sgpr_broadcast(al * az + be * bz + ga * cz);
    }

    // ---- j loop ----
    int count = 0;
#pragma unroll 2
    for (int k = 0; k < F; k += BLOCK) {
        int j = k + tid;
        if (j >= F) break;
        float4 cj = cent[j];                         // coalesced
        float dx = cix - cj.x, dy = ciy - cj.y, dz = ciz - cj.z;
        float d2 = dx * dx + dy * dy + dz * dz;
        if ((d2 < 1.0f) && (j != i)) {
            float4 a = g0[j];
            float4 b = g1[j];
            float best = -1.0f;
#pragma unroll
            for (int s = 0; s < SS; ++s) {
                float vv = fmaf(sz[s], a.z, fmaf(sy[s], a.y, fmaf(sx[s], a.x, a.w)));
                float ww = fmaf(sz[s], b.z, fmaf(sy[s], b.y, fmaf(sx[s], b.x, b.w)));
                float uu = 1.0f - vv - ww;
                best = fmaxf(best, fminf(uu, fminf(vv, ww)));
            }
            count += (best >= 0.0f) ? 1 : 0;
        }
    }

    // ---- block reduce ----
    for (int off = 32; off > 0; off >>= 1)
        count += __shfl_down(count, off, 64);
    __shared__ int wave_cnt[BLOCK / 64];
    __shared__ int lastFlag;
    if ((tid & 63) == 0) wave_cnt[tid >> 6] = count;
    __syncthreads();
    if (tid == 0) {
        int tot = 0;
#pragma unroll
        for (int w = 0; w < BLOCK / 64; ++w) tot += wave_cnt[w];
        float p = face_probs[i] * (float)tot;
        __hip_atomic_store(&partial[i], p, __ATOMIC_RELEASE, __HIP_MEMORY_SCOPE_AGENT);
        __threadfence();
        // two-level done counting (avoid 2048-way same-address contention)
        int g = i & 31;
        int members = (F - 1 - g) / 32 + 1;
        int last = 0;
        if (atomicAdd(&done1[g * 32], 1) == members - 1) {
            int ngroups = (F < 32) ? F : 32;
            last = (atomicAdd(done2, 1) == ngroups - 1) ? 1 : 0;
        }
        lastFlag = last;
    }
    __syncthreads();

    // ---- last block: final reduction over all partials ----
    if (lastFlag) {
        __threadfence();
        float sum = 0.0f;
        for (int f = tid; f < F; f += BLOCK)
            sum += __hip_atomic_load(&partial[f], __ATOMIC_RELAXED,
                                     __HIP_MEMORY_SCOPE_AGENT);
        for (int off = 32; off > 0; off >>= 1)
            sum += __shfl_down(sum, off, 64);
        __shared__ float wave_sum[BLOCK / 64];
        if ((tid & 63) == 0) wave_sum[tid >> 6] = sum;
        __syncthreads();
        if (tid == 0) {
            float tot = 0.0f;
#pragma unroll
            for (int w = 0; w < BLOCK / 64; ++w) tot += wave_sum[w];
            out[0] = tot / (float)F;
        }
    }
}

// Generic-S fallback (samples staged in LDS). Same structure.
#define MAXS_G 64
__global__ void __launch_bounds__(BLOCK)
pair_kernel_generic(const float4* __restrict__ cent,
                    const float4* __restrict__ g0,
                    const float4* __restrict__ g1,
                    const float* __restrict__ verts,
                    const int* __restrict__ faces,
                    const float* __restrict__ alpha,
                    const float* __restrict__ beta,
                    const float* __restrict__ face_probs,
                    int F, int S,
                    float* __restrict__ partial,
                    int* __restrict__ done1,
                    int* __restrict__ done2,
                    float* __restrict__ out) {
    const int i = blockIdx.x;
    const int tid = threadIdx.x;
    __shared__ float s_x[MAXS_G], s_y[MAXS_G], s_z[MAXS_G];

    int i0 = faces[3 * i + 0];
    int i1 = faces[3 * i + 1];
    int i2 = faces[3 * i + 2];
    float ax = verts[3 * i0 + 0], ay = verts[3 * i0 + 1], az = verts[3 * i0 + 2];
    float bx = verts[3 * i1 + 0], by = verts[3 * i1 + 1], bz = verts[3 * i1 + 2];
    float cx = verts[3 * i2 + 0], cy = verts[3 * i2 + 1], cz = verts[3 * i2 + 2];
    const float third = 1.0f / 3.0f;
    float cix = (ax + bx + cx) * third;
    float ciy = (ay + by + cy) * third;
    float ciz = (az + bz + cz) * third;
    for (int s = tid; s < S; s += BLOCK) {
        float al = alpha[(long long)i * S + s];
        float be = beta[(long long)i * S + s];
        float ga = 1.0f - al - be;
        s_x[s] = al * ax + be * bx + ga * cx;
        s_y[s] = al * ay + be * by + ga * cy;
        s_z[s] = al * az + be * bz + ga * cz;
    }
    __syncthreads();

    int count = 0;
    for (int k = 0; k < F; k += BLOCK) {
        int j = k + tid;
        if (j >= F) break;
        float4 cj = cent[j];
        float dx = cix - cj.x, dy = ciy - cj.y, dz = ciz - cj.z;
        float d2 = dx * dx + dy * dy + dz * dz;
        if ((d2 < 1.0f) && (j != i)) {
            float4 a = g0[j];
            float4 b = g1[j];
            float best = -1.0f;
            for (int s = 0; s < S; ++s) {
                float vv = fmaf(s_z[s], a.z, fmaf(s_y[s], a.y, fmaf(s_x[s], a.x, a.w)));
                float ww = fmaf(s_z[s], b.z, fmaf(s_y[s], b.y, fmaf(s_x[s], b.x, b.w)));
                float uu = 1.0f - vv - ww;
                best = fmaxf(best, fminf(uu, fminf(vv, ww)));
            }
            count += (best >= 0.0f) ? 1 : 0;
        }
    }

    for (int off = 32; off > 0; off >>= 1)
        count += __shfl_down(count, off, 64);
    __shared__ int wave_cnt[BLOCK / 64];
    __shared__ int lastFlag;
    if ((tid & 63) == 0) wave_cnt[tid >> 6] = count;
    __syncthreads();
    if (tid == 0) {
        int tot = 0;
#pragma unroll
        for (int w = 0; w < BLOCK / 64; ++w) tot += wave_cnt[w];
        float p = face_probs[i] * (float)tot;
        __hip_atomic_store(&partial[i], p, __ATOMIC_RELEASE, __HIP_MEMORY_SCOPE_AGENT);
        __threadfence();
        int g = i & 31;
        int members = (F - 1 - g) / 32 + 1;
        int last = 0;
        if (atomicAdd(&done1[g * 32], 1) == members - 1) {
            int ngroups = (F < 32) ? F : 32;
            last = (atomicAdd(done2, 1) == ngroups - 1) ? 1 : 0;
        }
        lastFlag = last;
    }
    __syncthreads();
    if (lastFlag) {
        __threadfence();
        float sum = 0.0f;
        for (int f = tid; f < F; f += BLOCK)
            sum += __hip_atomic_load(&partial[f], __ATOMIC_RELAXED,
                                     __HIP_MEMORY_SCOPE_AGENT);
        for (int off = 32; off > 0; off >>= 1)
            sum += __shfl_down(sum, off, 64);
        __shared__ float wave_sum[BLOCK / 64];
        if ((tid & 63) == 0) wave_sum[tid >> 6] = sum;
        __syncthreads();
        if (tid == 0) {
            float tot = 0.0f;
#pragma unroll
            for (int w = 0; w < BLOCK / 64; ++w) tot += wave_sum[w];
            out[0] = tot / (float)F;
        }
    }
}

extern "C" void kernel_launch(void* const* d_in, const int* in_sizes, int n_in,
                              void* d_out, int out_size, void* d_ws, size_t ws_size,
                              hipStream_t stream) {
    const float* vertices   = (const float*)d_in[0];
    const int*   faces      = (const int*)d_in[1];
    const float* face_probs = (const float*)d_in[2];
    const float* alpha      = (const float*)d_in[3];
    const float* beta       = (const float*)d_in[4];
    float* out = (float*)d_out;

    const int F = in_sizes[2];
    const int S = in_sizes[3] / F;

    // Workspace: cent[F], g0[F], g1[F] (float4), partial[F] (float),
    // done1[32*32] (int, 128B-strided counters), done2[1].
    char* ws = (char*)d_ws;
    float4* cent = (float4*)ws;
    float4* g0   = cent + F;
    float4* g1   = g0 + F;
    float*  partial = (float*)(g1 + F);
    int*    done1   = (int*)(partial + F);
    int*    done2   = done1 + 32 * 32;

    face_pre_kernel<<<(F + BLOCK - 1) / BLOCK, BLOCK, 0, stream>>>(
        vertices, faces, F, cent, g0, g1, done1, done2);

    if (S == 10) {
        pair_kernel<10><<<F, BLOCK, 0, stream>>>(
            cent, g0, g1, vertices, faces, alpha, beta, face_probs, F,
            partial, done1, done2, out);
    } else {
        pair_kernel_generic<<<F, BLOCK, 0, stream>>>(
            cent, g0, g1, vertices, faces, alpha, beta, face_probs, F, S,
            partial, done1, done2, out);
    }
}

// Round 5
// 82.636 us; speedup vs baseline: 1.5042x; 1.5042x over previous
//
#include <hip/hip_runtime.h>

#define BLOCK 256

// ---------------------------------------------------------------------------
// Kernel 1: per-face precompute.
//   cent[f]      = centroid (xyz)
//   g0[f] = (gv.xyz, cv)  with  gv = A*e0 - B*e1,  cv = B*w1e1 - A*w1e0
//   g1[f] = (gw.xyz, cw)  with  gw = C*e1 - B*e0,  cw = B*w1e0 - C*w1e1
//   spts[f*S+s]  = sample point s of face f (xyz)
// so that for a sample point p of face i against face j:
//   v = dot(p,gv_j)+cv_j, w = dot(p,gw_j)+cw_j, u = 1-v-w
// (A=d11/denom, B=d01/denom, C=d00/denom of face j).
// ---------------------------------------------------------------------------
__global__ void face_pre_kernel(const float* __restrict__ verts,
                                const int* __restrict__ faces,
                                const float* __restrict__ alpha,
                                const float* __restrict__ beta,
                                int F, int S,
                                float4* __restrict__ cent,
                                float4* __restrict__ g0,
                                float4* __restrict__ g1,
                                float4* __restrict__ spts) {
    int f = blockIdx.x * blockDim.x + threadIdx.x;
    if (f >= F) return;
    int i0 = faces[3 * f + 0];
    int i1 = faces[3 * f + 1];
    int i2 = faces[3 * f + 2];
    float ax = verts[3 * i0 + 0], ay = verts[3 * i0 + 1], az = verts[3 * i0 + 2];
    float bx = verts[3 * i1 + 0], by = verts[3 * i1 + 1], bz = verts[3 * i1 + 2];
    float cx = verts[3 * i2 + 0], cy = verts[3 * i2 + 1], cz = verts[3 * i2 + 2];

    float e0x = bx - ax, e0y = by - ay, e0z = bz - az;
    float e1x = cx - ax, e1y = cy - ay, e1z = cz - az;

    float d00 = e0x * e0x + e0y * e0y + e0z * e0z;
    float d01 = e0x * e1x + e0y * e1y + e0z * e1z;
    float d11 = e1x * e1x + e1y * e1y + e1z * e1z;
    float inv = 1.0f / (d00 * d11 - d01 * d01);
    float A = d11 * inv, B = d01 * inv, C = d00 * inv;

    float w1e0 = ax * e0x + ay * e0y + az * e0z;
    float w1e1 = ax * e1x + ay * e1y + az * e1z;

    const float third = 1.0f / 3.0f;
    cent[f] = make_float4((ax + bx + cx) * third,
                          (ay + by + cy) * third,
                          (az + bz + cz) * third, 0.0f);
    g0[f] = make_float4(A * e0x - B * e1x, A * e0y - B * e1y, A * e0z - B * e1z,
                        B * w1e1 - A * w1e0);
    g1[f] = make_float4(C * e1x - B * e0x, C * e1y - B * e0y, C * e1z - B * e0z,
                        B * w1e0 - C * w1e1);

    for (int s = 0; s < S; ++s) {
        float al = alpha[(long long)f * S + s];
        float be = beta[(long long)f * S + s];
        float ga = 1.0f - al - be;
        spts[(long long)f * S + s] =
            make_float4(al * ax + be * bx + ga * cx,
                        al * ay + be * by + ga * cy,
                        al * az + be * bz + ga * cz, 0.0f);
    }
}

// ---------------------------------------------------------------------------
// Kernel 2: pair kernel. One block per i. Prologue: uniform (blockIdx-
// indexed) loads of cent[i] and the S precomputed sample points -> compiler
// emits scalar s_load into SGPRs (no VMEM chain, no readfirstlane).
// j-loop: 3 coalesced float4 loads + dist test + S branchless sample tests.
// Epilogue: wave shuffle reduce -> LDS -> one plain store (no atomics).
// ---------------------------------------------------------------------------
template <int SS>
__global__ void __launch_bounds__(BLOCK)
pair_kernel(const float4* __restrict__ cent,
            const float4* __restrict__ g0,
            const float4* __restrict__ g1,
            const float4* __restrict__ spts,
            const float* __restrict__ face_probs,
            int F,
            float* __restrict__ partial) {
    const int i = blockIdx.x;
    const int tid = threadIdx.x;

    // ---- uniform prologue (scalar loads) ----
    const float4 ci = cent[i];
    float sx[SS], sy[SS], sz[SS];
#pragma unroll
    for (int s = 0; s < SS; ++s) {
        float4 p = spts[i * SS + s];
        sx[s] = p.x; sy[s] = p.y; sz[s] = p.z;
    }

    // ---- j loop ----
    int count = 0;
#pragma unroll 2
    for (int j = tid; j < F; j += BLOCK) {
        float4 cj = cent[j];                         // coalesced
        float dx = ci.x - cj.x, dy = ci.y - cj.y, dz = ci.z - cj.z;
        float d2 = dx * dx + dy * dy + dz * dz;
        if ((d2 < 1.0f) && (j != i)) {
            float4 a = g0[j];
            float4 b = g1[j];
            float best = -1.0f;
#pragma unroll
            for (int s = 0; s < SS; ++s) {
                float vv = fmaf(sz[s], a.z, fmaf(sy[s], a.y, fmaf(sx[s], a.x, a.w)));
                float ww = fmaf(sz[s], b.z, fmaf(sy[s], b.y, fmaf(sx[s], b.x, b.w)));
                float uu = 1.0f - vv - ww;
                best = fmaxf(best, fminf(uu, fminf(vv, ww)));
            }
            count += (best >= 0.0f) ? 1 : 0;
        }
    }

    // ---- block reduce: wave shuffle -> LDS -> single plain store ----
    for (int off = 32; off > 0; off >>= 1)
        count += __shfl_down(count, off, 64);
    __shared__ int wave_cnt[BLOCK / 64];
    if ((tid & 63) == 0) wave_cnt[tid >> 6] = count;
    __syncthreads();
    if (tid == 0) {
        int tot = 0;
#pragma unroll
        for (int w = 0; w < BLOCK / 64; ++w) tot += wave_cnt[w];
        partial[i] = face_probs[i] * (float)tot;     // unique slot, no atomic
    }
}

// Generic-S fallback: sample points staged in LDS.
#define MAXS_G 64
__global__ void __launch_bounds__(BLOCK)
pair_kernel_generic(const float4* __restrict__ cent,
                    const float4* __restrict__ g0,
                    const float4* __restrict__ g1,
                    const float4* __restrict__ spts,
                    const float* __restrict__ face_probs,
                    int F, int S,
                    float* __restrict__ partial) {
    const int i = blockIdx.x;
    const int tid = threadIdx.x;
    __shared__ float s_x[MAXS_G], s_y[MAXS_G], s_z[MAXS_G];
    for (int s = tid; s < S; s += BLOCK) {
        float4 p = spts[(long long)i * S + s];
        s_x[s] = p.x; s_y[s] = p.y; s_z[s] = p.z;
    }
    __syncthreads();
    const float4 ci = cent[i];

    int count = 0;
    for (int j = tid; j < F; j += BLOCK) {
        float4 cj = cent[j];
        float dx = ci.x - cj.x, dy = ci.y - cj.y, dz = ci.z - cj.z;
        float d2 = dx * dx + dy * dy + dz * dz;
        if ((d2 < 1.0f) && (j != i)) {
            float4 a = g0[j];
            float4 b = g1[j];
            float best = -1.0f;
            for (int s = 0; s < S; ++s) {
                float vv = fmaf(s_z[s], a.z, fmaf(s_y[s], a.y, fmaf(s_x[s], a.x, a.w)));
                float ww = fmaf(s_z[s], b.z, fmaf(s_y[s], b.y, fmaf(s_x[s], b.x, b.w)));
                float uu = 1.0f - vv - ww;
                best = fmaxf(best, fminf(uu, fminf(vv, ww)));
            }
            count += (best >= 0.0f) ? 1 : 0;
        }
    }

    for (int off = 32; off > 0; off >>= 1)
        count += __shfl_down(count, off, 64);
    __shared__ int wave_cnt[BLOCK / 64];
    if ((tid & 63) == 0) wave_cnt[tid >> 6] = count;
    __syncthreads();
    if (tid == 0) {
        int tot = 0;
#pragma unroll
        for (int w = 0; w < BLOCK / 64; ++w) tot += wave_cnt[w];
        partial[i] = face_probs[i] * (float)tot;
    }
}

// ---------------------------------------------------------------------------
// Kernel 3: reduce partial[0..F) -> out[0] = sum / F. Single block.
// ---------------------------------------------------------------------------
__global__ void __launch_bounds__(BLOCK)
reduce_kernel(const float* __restrict__ partial, float* __restrict__ out,
              int F, float invF) {
    const int tid = threadIdx.x;
    float sum = 0.0f;
    for (int f = tid; f < F; f += BLOCK) sum += partial[f];
    for (int off = 32; off > 0; off >>= 1)
        sum += __shfl_down(sum, off, 64);
    __shared__ float wave_sum[BLOCK / 64];
    if ((tid & 63) == 0) wave_sum[tid >> 6] = sum;
    __syncthreads();
    if (tid == 0) {
        float tot = 0.0f;
#pragma unroll
        for (int w = 0; w < BLOCK / 64; ++w) tot += wave_sum[w];
        out[0] = tot * invF;
    }
}

extern "C" void kernel_launch(void* const* d_in, const int* in_sizes, int n_in,
                              void* d_out, int out_size, void* d_ws, size_t ws_size,
                              hipStream_t stream) {
    const float* vertices   = (const float*)d_in[0];
    const int*   faces      = (const int*)d_in[1];
    const float* face_probs = (const float*)d_in[2];
    const float* alpha      = (const float*)d_in[3];
    const float* beta       = (const float*)d_in[4];
    float* out = (float*)d_out;

    const int F = in_sizes[2];
    const int S = in_sizes[3] / F;

    // Workspace: cent[F], g0[F], g1[F], spts[F*S] (float4), partial[F].
    char* ws = (char*)d_ws;
    float4* cent = (float4*)ws;
    float4* g0   = cent + F;
    float4* g1   = g0 + F;
    float4* spts = g1 + F;
    float*  partial = (float*)(spts + (long long)F * S);

    face_pre_kernel<<<(F + BLOCK - 1) / BLOCK, BLOCK, 0, stream>>>(
        vertices, faces, alpha, beta, F, S, cent, g0, g1, spts);

    if (S == 10) {
        pair_kernel<10><<<F, BLOCK, 0, stream>>>(
            cent, g0, g1, spts, face_probs, F, partial);
    } else {
        pair_kernel_generic<<<F, BLOCK, 0, stream>>>(
            cent, g0, g1, spts, face_probs, F, S, partial);
    }

    reduce_kernel<<<1, BLOCK, 0, stream>>>(partial, out, F, 1.0f / (float)F);
}

// Round 6
// 80.921 us; speedup vs baseline: 1.5360x; 1.0212x over previous
//
#include <hip/hip_runtime.h>

#define BLOCK 256

// ---------------------------------------------------------------------------
// Kernel 1: per-face precompute.
//   cent[f]      = centroid (xyz)
//   g0[f] = (gv.xyz, cv)  with  gv = A*e0 - B*e1,  cv = B*w1e1 - A*w1e0
//   g1[f] = (gw.xyz, cw)  with  gw = C*e1 - B*e0,  cw = B*w1e0 - C*w1e1
//   spts[f*S+s]  = sample point s of face f (xyz)
// For sample point p of face i vs face j:
//   v = dot(p,gv_j)+cv_j, w = dot(p,gw_j)+cw_j, u = 1-v-w
// ---------------------------------------------------------------------------
__global__ void face_pre_kernel(const float* __restrict__ verts,
                                const int* __restrict__ faces,
                                const float* __restrict__ alpha,
                                const float* __restrict__ beta,
                                int F, int S,
                                float4* __restrict__ cent,
                                float4* __restrict__ g0,
                                float4* __restrict__ g1,
                                float4* __restrict__ spts) {
    int f = blockIdx.x * blockDim.x + threadIdx.x;
    if (f >= F) return;
    int i0 = faces[3 * f + 0];
    int i1 = faces[3 * f + 1];
    int i2 = faces[3 * f + 2];
    float ax = verts[3 * i0 + 0], ay = verts[3 * i0 + 1], az = verts[3 * i0 + 2];
    float bx = verts[3 * i1 + 0], by = verts[3 * i1 + 1], bz = verts[3 * i1 + 2];
    float cx = verts[3 * i2 + 0], cy = verts[3 * i2 + 1], cz = verts[3 * i2 + 2];

    float e0x = bx - ax, e0y = by - ay, e0z = bz - az;
    float e1x = cx - ax, e1y = cy - ay, e1z = cz - az;

    float d00 = e0x * e0x + e0y * e0y + e0z * e0z;
    float d01 = e0x * e1x + e0y * e1y + e0z * e1z;
    float d11 = e1x * e1x + e1y * e1y + e1z * e1z;
    float inv = 1.0f / (d00 * d11 - d01 * d01);
    float A = d11 * inv, B = d01 * inv, C = d00 * inv;

    float w1e0 = ax * e0x + ay * e0y + az * e0z;
    float w1e1 = ax * e1x + ay * e1y + az * e1z;

    const float third = 1.0f / 3.0f;
    cent[f] = make_float4((ax + bx + cx) * third,
                          (ay + by + cy) * third,
                          (az + bz + cz) * third, 0.0f);
    g0[f] = make_float4(A * e0x - B * e1x, A * e0y - B * e1y, A * e0z - B * e1z,
                        B * w1e1 - A * w1e0);
    g1[f] = make_float4(C * e1x - B * e0x, C * e1y - B * e0y, C * e1z - B * e0z,
                        B * w1e0 - C * w1e1);

    for (int s = 0; s < S; ++s) {
        float al = alpha[(long long)f * S + s];
        float be = beta[(long long)f * S + s];
        float ga = 1.0f - al - be;
        spts[(long long)f * S + s] =
            make_float4(al * ax + be * bx + ga * cx,
                        al * ay + be * by + ga * cy,
                        al * az + be * bz + ga * cz, 0.0f);
    }
}

// ---------------------------------------------------------------------------
// Kernel 2: pair kernel with intra-block compaction.
// One block per i.
//   Phase 1: threads test dist over all F j's (centroid loads prefetched
//            one iteration ahead); passing j's pushed to an LDS queue via
//            ballot + mbcnt prefix + one ds-atomic per wave.
//   Phase 2: threads process the compacted queue with FULL lane utilization
//            (~0.32*F entries instead of F masked ones).
// Epilogue: shuffle reduce -> LDS -> one plain store (no atomics).
// Dynamic LDS: F ints (queue).
// ---------------------------------------------------------------------------
template <int SS>
__global__ void __launch_bounds__(BLOCK)
pair_kernel(const float4* __restrict__ cent,
            const float4* __restrict__ g0,
            const float4* __restrict__ g1,
            const float4* __restrict__ spts,
            const float* __restrict__ face_probs,
            int F,
            float* __restrict__ partial) {
    const int i = blockIdx.x;
    const int tid = threadIdx.x;
    const int lane = tid & 63;

    extern __shared__ int s_queue[];   // F ints
    __shared__ int s_n;
    __shared__ int wave_cnt[BLOCK / 64];
    if (tid == 0) s_n = 0;

    // ---- uniform prologue (scalar loads) ----
    const float4 ci = cent[i];
    float sx[SS], sy[SS], sz[SS];
#pragma unroll
    for (int s = 0; s < SS; ++s) {
        float4 p = spts[i * SS + s];
        sx[s] = p.x; sy[s] = p.y; sz[s] = p.z;
    }
    __syncthreads();

    // ---- phase 1: dist test + compaction into LDS queue ----
    float4 c_next = (tid < F) ? cent[tid] : make_float4(1e30f, 1e30f, 1e30f, 0.f);
    for (int k = 0; k < F; k += BLOCK) {
        int j = k + tid;
        float4 c = c_next;
        int jn = k + BLOCK + tid;
        if (jn < F) c_next = cent[jn];             // prefetch next iter
        float dx = ci.x - c.x, dy = ci.y - c.y, dz = ci.z - c.z;
        float d2 = dx * dx + dy * dy + dz * dz;
        bool pass = (j < F) && (d2 < 1.0f) && (j != i);
        unsigned long long m = __ballot(pass);
        int prefix = __builtin_amdgcn_mbcnt_hi((unsigned int)(m >> 32),
                     __builtin_amdgcn_mbcnt_lo((unsigned int)m, 0));
        int wtotal = __popcll(m);
        int base = 0;
        if (lane == 0 && wtotal) base = atomicAdd(&s_n, wtotal);
        base = __shfl(base, 0, 64);
        if (pass) s_queue[base + prefix] = j;
    }
    __syncthreads();
    const int n = s_n;

    // ---- phase 2: dense barycentric tests over compacted queue ----
    int count = 0;
    for (int k = tid; k < n; k += BLOCK) {
        int j = s_queue[k];
        float4 a = g0[j];
        float4 b = g1[j];
        float best = -1.0f;
#pragma unroll
        for (int s = 0; s < SS; ++s) {
            float vv = fmaf(sz[s], a.z, fmaf(sy[s], a.y, fmaf(sx[s], a.x, a.w)));
            float ww = fmaf(sz[s], b.z, fmaf(sy[s], b.y, fmaf(sx[s], b.x, b.w)));
            float uu = 1.0f - vv - ww;
            best = fmaxf(best, fminf(uu, fminf(vv, ww)));
        }
        count += (best >= 0.0f) ? 1 : 0;
    }

    // ---- block reduce: wave shuffle -> LDS -> single plain store ----
    for (int off = 32; off > 0; off >>= 1)
        count += __shfl_down(count, off, 64);
    if (lane == 0) wave_cnt[tid >> 6] = count;
    __syncthreads();
    if (tid == 0) {
        int tot = 0;
#pragma unroll
        for (int w = 0; w < BLOCK / 64; ++w) tot += wave_cnt[w];
        partial[i] = face_probs[i] * (float)tot;     // unique slot, no atomic
    }
}

// Generic-S fallback (no compaction, samples in LDS).
#define MAXS_G 64
__global__ void __launch_bounds__(BLOCK)
pair_kernel_generic(const float4* __restrict__ cent,
                    const float4* __restrict__ g0,
                    const float4* __restrict__ g1,
                    const float4* __restrict__ spts,
                    const float* __restrict__ face_probs,
                    int F, int S,
                    float* __restrict__ partial) {
    const int i = blockIdx.x;
    const int tid = threadIdx.x;
    __shared__ float s_x[MAXS_G], s_y[MAXS_G], s_z[MAXS_G];
    for (int s = tid; s < S; s += BLOCK) {
        float4 p = spts[(long long)i * S + s];
        s_x[s] = p.x; s_y[s] = p.y; s_z[s] = p.z;
    }
    __syncthreads();
    const float4 ci = cent[i];

    int count = 0;
    for (int j = tid; j < F; j += BLOCK) {
        float4 cj = cent[j];
        float dx = ci.x - cj.x, dy = ci.y - cj.y, dz = ci.z - cj.z;
        float d2 = dx * dx + dy * dy + dz * dz;
        if ((d2 < 1.0f) && (j != i)) {
            float4 a = g0[j];
            float4 b = g1[j];
            float best = -1.0f;
            for (int s = 0; s < S; ++s) {
                float vv = fmaf(s_z[s], a.z, fmaf(s_y[s], a.y, fmaf(s_x[s], a.x, a.w)));
                float ww = fmaf(s_z[s], b.z, fmaf(s_y[s], b.y, fmaf(s_x[s], b.x, b.w)));
                float uu = 1.0f - vv - ww;
                best = fmaxf(best, fminf(uu, fminf(vv, ww)));
            }
            count += (best >= 0.0f) ? 1 : 0;
        }
    }

    for (int off = 32; off > 0; off >>= 1)
        count += __shfl_down(count, off, 64);
    __shared__ int wave_cnt[BLOCK / 64];
    if ((tid & 63) == 0) wave_cnt[tid >> 6] = count;
    __syncthreads();
    if (tid == 0) {
        int tot = 0;
#pragma unroll
        for (int w = 0; w < BLOCK / 64; ++w) tot += wave_cnt[w];
        partial[i] = face_probs[i] * (float)tot;
    }
}

// ---------------------------------------------------------------------------
// Kernel 3: reduce partial[0..F) -> out[0] = sum / F. Single block.
// ---------------------------------------------------------------------------
__global__ void __launch_bounds__(BLOCK)
reduce_kernel(const float* __restrict__ partial, float* __restrict__ out,
              int F, float invF) {
    const int tid = threadIdx.x;
    float sum = 0.0f;
    for (int f = tid; f < F; f += BLOCK) sum += partial[f];
    for (int off = 32; off > 0; off >>= 1)
        sum += __shfl_down(sum, off, 64);
    __shared__ float wave_sum[BLOCK / 64];
    if ((tid & 63) == 0) wave_sum[tid >> 6] = sum;
    __syncthreads();
    if (tid == 0) {
        float tot = 0.0f;
#pragma unroll
        for (int w = 0; w < BLOCK / 64; ++w) tot += wave_sum[w];
        out[0] = tot * invF;
    }
}

extern "C" void kernel_launch(void* const* d_in, const int* in_sizes, int n_in,
                              void* d_out, int out_size, void* d_ws, size_t ws_size,
                              hipStream_t stream) {
    const float* vertices   = (const float*)d_in[0];
    const int*   faces      = (const int*)d_in[1];
    const float* face_probs = (const float*)d_in[2];
    const float* alpha      = (const float*)d_in[3];
    const float* beta       = (const float*)d_in[4];
    float* out = (float*)d_out;

    const int F = in_sizes[2];
    const int S = in_sizes[3] / F;

    // Workspace: cent[F], g0[F], g1[F], spts[F*S] (float4), partial[F].
    char* ws = (char*)d_ws;
    float4* cent = (float4*)ws;
    float4* g0   = cent + F;
    float4* g1   = g0 + F;
    float4* spts = g1 + F;
    float*  partial = (float*)(spts + (long long)F * S);

    face_pre_kernel<<<(F + BLOCK - 1) / BLOCK, BLOCK, 0, stream>>>(
        vertices, faces, alpha, beta, F, S, cent, g0, g1, spts);

    if (S == 10) {
        size_t lds = (size_t)F * sizeof(int);
        pair_kernel<10><<<F, BLOCK, lds, stream>>>(
            cent, g0, g1, spts, face_probs, F, partial);
    } else {
        pair_kernel_generic<<<F, BLOCK, 0, stream>>>(
            cent, g0, g1, spts, face_probs, F, S, partial);
    }

    reduce_kernel<<<1, BLOCK, 0, stream>>>(partial, out, F, 1.0f / (float)F);
}